// Round 4
// baseline (16986.111 us; speedup 1.0000x reference)
//
#include <hip/hip_runtime.h>
#include <hip/hip_bf16.h>
#include <cstdint>

typedef __attribute__((ext_vector_type(4))) float floatx4;
typedef __attribute__((ext_vector_type(8))) __bf16 bf16x8;
typedef __attribute__((ext_vector_type(4))) __bf16 bf16x4;
typedef unsigned long long u64t;

#define HID    1024
#define SEQ    4096
#define TGT    1024
#define ENC_T  3072
#define IN_DIM 544
#define NCLS   50000

// ---------------- embed: x = [emb_loc[loc] | emb_tim[tim]] ----------------
__global__ __launch_bounds__(128) void embed_kernel(
    const int* __restrict__ loc, const int* __restrict__ tim,
    const float* __restrict__ el, const float* __restrict__ et,
    float* __restrict__ x) {
  int row = blockIdx.x, t = threadIdx.x;
  int li = loc[row], ti = tim[row];
  float4 v = *(const float4*)(el + (size_t)li * 512 + t * 4);
  *(float4*)(x + (size_t)row * IN_DIM + t * 4) = v;
  if (t < 8) {
    float4 w = *(const float4*)(et + (size_t)ti * 32 + t * 4);
    *(float4*)(x + (size_t)row * IN_DIM + 512 + t * 4) = w;
  }
}

// ---------------- generic NT GEMM: C[M,N] = A[M,K] @ B[N,K]^T (+bias[n]) --
#define BK  64
#define LDT 72   // 64 + 8 bf16 pad; row stride 144 B (16-aligned)

__global__ __launch_bounds__(256) void gemm_nt(
    const float* __restrict__ A, int lda,
    const float* __restrict__ B, int ldb,
    float* __restrict__ C, int ldc,
    const float* __restrict__ bias,
    int M, int N, int K) {
  __shared__ __bf16 As[128 * LDT];
  __shared__ __bf16 Bs[128 * LDT];
  const int tid = threadIdx.x;
  const int bm = blockIdx.x * 128, bn = blockIdx.y * 128;
  const int wave = tid >> 6, lane = tid & 63;
  const int wm = (wave & 1) * 64, wn = (wave >> 1) * 64;
  const int fr = lane & 15;
  const int kq = (lane >> 4) * 8;

  floatx4 acc[4][4];
#pragma unroll
  for (int i = 0; i < 4; i++)
#pragma unroll
    for (int j = 0; j < 4; j++) acc[i][j] = (floatx4){0.f, 0.f, 0.f, 0.f};

  const int nkt = (K + BK - 1) / BK;
  for (int kt = 0; kt < nkt; ++kt) {
    const int k0 = kt * BK;
#pragma unroll
    for (int i = 0; i < 8; i++) {
      int flat = tid + i * 256;       // 2048 float4 slots: 128 rows x 16
      int r = flat >> 4;
      int c4 = (flat & 15) * 4;
      float4 va = {0, 0, 0, 0}, vb = {0, 0, 0, 0};
      if (k0 + c4 < K) {
        va = *(const float4*)(A + (size_t)(bm + r) * lda + k0 + c4);
        if (bn + r < N) vb = *(const float4*)(B + (size_t)(bn + r) * ldb + k0 + c4);
      }
      *(bf16x4*)(As + r * LDT + c4) =
          (bf16x4){(__bf16)va.x, (__bf16)va.y, (__bf16)va.z, (__bf16)va.w};
      *(bf16x4*)(Bs + r * LDT + c4) =
          (bf16x4){(__bf16)vb.x, (__bf16)vb.y, (__bf16)vb.z, (__bf16)vb.w};
    }
    __syncthreads();
#pragma unroll
    for (int kh = 0; kh < 2; ++kh) {
      const int kf = kh * 32 + kq;
      bf16x8 af[4], bfr[4];
#pragma unroll
      for (int i = 0; i < 4; i++) {
        af[i]  = *(const bf16x8*)(As + (wm + i * 16 + fr) * LDT + kf);
        bfr[i] = *(const bf16x8*)(Bs + (wn + i * 16 + fr) * LDT + kf);
      }
#pragma unroll
      for (int mi = 0; mi < 4; mi++)
#pragma unroll
        for (int ni = 0; ni < 4; ni++)
          acc[mi][ni] = __builtin_amdgcn_mfma_f32_16x16x32_bf16(
              af[mi], bfr[ni], acc[mi][ni], 0, 0, 0);
    }
    __syncthreads();
  }

  const int em = (lane >> 4) * 4;
#pragma unroll
  for (int mi = 0; mi < 4; mi++) {
#pragma unroll
    for (int ni = 0; ni < 4; ni++) {
      int gn = bn + wn + ni * 16 + fr;
      if (gn < N) {
        float bv = bias ? bias[gn] : 0.f;
        int gm = bm + wm + mi * 16 + em;
#pragma unroll
        for (int r2 = 0; r2 < 4; r2++)
          C[(size_t)(gm + r2) * ldc + gn] = acc[mi][ni][r2] + bv;
      }
    }
  }
}

// ---------------- persistent GRU scan (enc: WG 0..127, dec: WG 128..255) --
// Compact stamped-h protocol: each h element is a 4B word {stamp:16|bf16(h):16}
// stored with a relaxed agent-scope atomic (stamp+payload in ONE dword: no
// tearing). Readers poll the data words (8 u64 loads/lane = 1 KB/wave/round,
// 8x less IF$ poll traffic than the 8B fp32 scheme -> no IF$ BW saturation).
// Owner's recurrent h is carried in an fp32 register (exact); only the
// broadcast used in bf16-weight dot products is bf16-rounded.
// No per-step __syncthreads: each wave self-gates (its store at step t
// requires all stamps >= t, which readers publish only AFTER consuming the
// parity this store overwrites). Waves run fully independently.
#define SC_WGS 128

__device__ __forceinline__ float flo(unsigned int u) {
  return __builtin_bit_cast(float, u << 16);
}
__device__ __forceinline__ float fhi(unsigned int u) {
  return __builtin_bit_cast(float, u & 0xffff0000u);
}

__global__ __launch_bounds__(256) void scan_kernel(
    const float* __restrict__ Whh_e, const float* __restrict__ bhh_e, const float* __restrict__ gi_e,
    const float* __restrict__ Whh_d, const float* __restrict__ bhh_d, const float* __restrict__ gi_d,
    float* __restrict__ Hh, float* __restrict__ HhT, float* __restrict__ outcat,
    unsigned int* __restrict__ hbuf_e, unsigned int* __restrict__ hbuf_d) {
  const bool enc = blockIdx.x < SC_WGS;
  const int wid = enc ? blockIdx.x : (blockIdx.x - SC_WGS);
  const int T = enc ? ENC_T : TGT;
  const float* Whh = enc ? Whh_e : Whh_d;
  const float* bhh = enc ? bhh_e : bhh_d;
  const float* gi  = enc ? gi_e : gi_d;
  unsigned int* hbuf = enc ? hbuf_e : hbuf_d;

  // weights: per local elem (8): r,z packed bf16x2 (uint2) + n packed (uint)
  // index i packs k = 2i (lo), 2i+1 (hi) -- matches the u64 h-load pairing.
  __shared__ uint2 wrz[8 * 512];          // 32 KB
  __shared__ unsigned int wnn[8 * 512];   // 16 KB
  const int tid = threadIdx.x;

  for (int i = tid; i < 8 * 512; i += 256) {
    int el = i >> 9, k2 = i & 511;
    int rb = wid * 8 + el;
    float2 w0 = *(const float2*)(Whh + (size_t)(0 * HID + rb) * HID + 2 * k2);
    float2 w1 = *(const float2*)(Whh + (size_t)(1 * HID + rb) * HID + 2 * k2);
    float2 w2 = *(const float2*)(Whh + (size_t)(2 * HID + rb) * HID + 2 * k2);
    unsigned int p0 = (unsigned int)__builtin_bit_cast(unsigned short, (__bf16)w0.x) |
                      ((unsigned int)__builtin_bit_cast(unsigned short, (__bf16)w0.y) << 16);
    unsigned int p1 = (unsigned int)__builtin_bit_cast(unsigned short, (__bf16)w1.x) |
                      ((unsigned int)__builtin_bit_cast(unsigned short, (__bf16)w1.y) << 16);
    unsigned int p2 = (unsigned int)__builtin_bit_cast(unsigned short, (__bf16)w2.x) |
                      ((unsigned int)__builtin_bit_cast(unsigned short, (__bf16)w2.y) << 16);
    wrz[i] = make_uint2(p0, p1);
    wnn[i] = p2;
  }
  __syncthreads();

  const int l = tid & 63;          // lane in wave
  const int w = tid >> 6;          // wave 0..3
  const int le0 = w * 2, le1 = le0 + 1;   // local elems this wave owns
  const int e0 = wid * 8 + le0;

  float bq = 0.f;
  if (l < 3) bq = bhh[l * HID + e0];
  else if (l >= 4 && l < 7) bq = bhh[(l - 4) * HID + (e0 + 1)];

  const uint2* wrz0 = wrz + le0 * 512;
  const uint2* wrz1 = wrz + le1 * 512;
  const unsigned int* wnn0 = wnn + le0 * 512;
  const unsigned int* wnn1 = wnn + le1 * 512;

  float h_own = 0.f;        // fp32 recurrent state for element e0+l (l<2)
  long budget = 1L << 21;   // global failed-round budget: fast-fail, no hang

  for (int t = 0; t < T; ++t) {
    float gval = 0.f;  // input-gate prefetch (stamp-independent, overlaps poll)
    if (l < 3) gval = gi[(size_t)t * 3072 + l * HID + e0];
    else if (l >= 4 && l < 7) gval = gi[(size_t)t * 3072 + (l - 4) * HID + (e0 + 1)];

    const u64t* hp = (const u64t*)(hbuf + ((t + 1) & 1) * HID);
    const unsigned int tlo = (unsigned int)t;
    float ar0, az0, an0, ar1, az1, an1;
    for (;;) {
      u64t hv[8];
#pragma unroll
      for (int j = 0; j < 8; ++j)
        hv[j] = __hip_atomic_load(hp + l + 64 * j, __ATOMIC_RELAXED, __HIP_MEMORY_SCOPE_AGENT);
      bool ok = true;
      ar0 = az0 = an0 = ar1 = az1 = an1 = 0.f;
#pragma unroll
      for (int j = 0; j < 8; ++j) {
        unsigned int w0 = (unsigned int)hv[j];
        unsigned int w1 = (unsigned int)(hv[j] >> 32);
        ok &= ((w0 >> 16) >= tlo) & ((w1 >> 16) >= tlo);
        float h0 = flo(w0);   // bf16 payload -> f32
        float h1 = flo(w1);
        int i = l + 64 * j;
        uint2 u0 = wrz0[i];
        unsigned int n0 = wnn0[i];
        uint2 u1 = wrz1[i];
        unsigned int n1 = wnn1[i];
        ar0 += flo(u0.x) * h0 + fhi(u0.x) * h1;
        az0 += flo(u0.y) * h0 + fhi(u0.y) * h1;
        an0 += flo(n0) * h0 + fhi(n0) * h1;
        ar1 += flo(u1.x) * h0 + fhi(u1.x) * h1;
        az1 += flo(u1.y) * h0 + fhi(u1.y) * h1;
        an1 += flo(n1) * h0 + fhi(n1) * h1;
      }
      if (__all(ok)) break;
      if (--budget < 0) break;   // bounded: fast wrong-result beats a hang
    }
    // full-wave butterfly reduce (each lane ends with the 6 sums)
#pragma unroll
    for (int o = 32; o; o >>= 1) {
      ar0 += __shfl_xor(ar0, o); az0 += __shfl_xor(az0, o); an0 += __shfl_xor(an0, o);
      ar1 += __shfl_xor(ar1, o); az1 += __shfl_xor(az1, o); an1 += __shfl_xor(an1, o);
    }
    int base = (l & 1) * 4;  // writer lane 0 -> gval lanes 0-2 (e0), lane 1 -> 4-6 (e0+1)
    float i_r = __shfl(gval, base + 0);
    float i_z = __shfl(gval, base + 1);
    float i_n = __shfl(gval, base + 2);
    float b_r = __shfl(bq, base + 0);
    float b_z = __shfl(bq, base + 1);
    float b_n = __shfl(bq, base + 2);
    if (l < 2) {
      float sr = l ? ar1 : ar0;
      float sz = l ? az1 : az0;
      float sn = l ? an1 : an0;
      int e = e0 + l;
      float r = 1.f / (1.f + expf(-(i_r + sr + b_r)));
      float z = 1.f / (1.f + expf(-(i_z + sz + b_z)));
      float nn2 = tanhf(i_n + r * (sn + b_n));
      float hnew = (1.f - z) * nn2 + z * h_own;
      h_own = hnew;
      unsigned int pk = ((unsigned int)(t + 1) << 16) |
                        (unsigned int)__builtin_bit_cast(unsigned short, (__bf16)hnew);
      __hip_atomic_store(&hbuf[(t & 1) * HID + e], pk,
                         __ATOMIC_RELAXED, __HIP_MEMORY_SCOPE_AGENT);
      if (enc) {
        Hh[(size_t)t * HID + e] = hnew;
        HhT[(size_t)e * ENC_T + t] = hnew;
      } else {
        outcat[(size_t)t * 2048 + e] = hnew;  // hidden_state -> out-concat cols 0..1023
      }
    }
  }
}

// ---------------- reductions ----------------
__device__ __forceinline__ float wave_max(float v) {
#pragma unroll
  for (int o = 32; o; o >>= 1) v = fmaxf(v, __shfl_xor(v, o));
  return v;
}
__device__ __forceinline__ float wave_sum(float v) {
#pragma unroll
  for (int o = 32; o; o >>= 1) v += __shfl_xor(v, o);
  return v;
}

// in-place row softmax over [TGT, ENC_T]
__global__ __launch_bounds__(256) void softmax_kernel(float* __restrict__ E) {
  __shared__ float red[4];
  int row = blockIdx.x;
  float* p = E + (size_t)row * ENC_T;
  int tid = threadIdx.x, wave = tid >> 6;
  float v[12];
  float m = -3.4e38f;
#pragma unroll
  for (int j = 0; j < 12; j++) { v[j] = p[tid + j * 256]; m = fmaxf(m, v[j]); }
  m = wave_max(m);
  if ((tid & 63) == 0) red[wave] = m;
  __syncthreads();
  m = fmaxf(fmaxf(red[0], red[1]), fmaxf(red[2], red[3]));
  __syncthreads();
  float s = 0.f;
#pragma unroll
  for (int j = 0; j < 12; j++) { v[j] = expf(v[j] - m); s += v[j]; }
  s = wave_sum(s);
  if ((tid & 63) == 0) red[wave] = s;
  __syncthreads();
  s = red[0] + red[1] + red[2] + red[3];
  float inv = 1.f / s;
#pragma unroll
  for (int j = 0; j < 12; j++) p[tid + j * 256] = v[j] * inv;
}

__global__ __launch_bounds__(256) void lse_kernel(const float* __restrict__ Y,
                                                  float* __restrict__ lse) {
  __shared__ float red[4];
  int row = blockIdx.x;
  const float* p = Y + (size_t)row * NCLS;
  int tid = threadIdx.x, wave = tid >> 6;
  float m = -3.4e38f;
  for (int c = tid; c < NCLS; c += 256) m = fmaxf(m, p[c]);
  m = wave_max(m);
  if ((tid & 63) == 0) red[wave] = m;
  __syncthreads();
  m = fmaxf(fmaxf(red[0], red[1]), fmaxf(red[2], red[3]));
  __syncthreads();
  float s = 0.f;
  for (int c = tid; c < NCLS; c += 256) s += expf(p[c] - m);
  s = wave_sum(s);
  if ((tid & 63) == 0) red[wave] = s;
  __syncthreads();
  if (tid == 0) lse[row] = m + logf(red[0] + red[1] + red[2] + red[3]);
}

__global__ __launch_bounds__(256) void sub_kernel(float* __restrict__ Y,
                                                  const float* __restrict__ lse) {
  const unsigned total = (unsigned)TGT * (NCLS / 4);
  unsigned stride = gridDim.x * 256;
  for (unsigned i = blockIdx.x * 256 + threadIdx.x; i < total; i += stride) {
    unsigned row = i / (NCLS / 4);
    float l = lse[row];
    float4 v = ((float4*)Y)[i];
    v.x -= l; v.y -= l; v.z -= l; v.w -= l;
    ((float4*)Y)[i] = v;
  }
}

// ---------------- launch ----------------
extern "C" void kernel_launch(void* const* d_in, const int* in_sizes, int n_in,
                              void* d_out, int out_size, void* d_ws, size_t ws_size,
                              hipStream_t stream) {
  const int*   loc     = (const int*)d_in[0];
  const int*   tim     = (const int*)d_in[1];
  // d_in[2] = target_len (fixed 1024, ignored)
  const float* emb_loc = (const float*)d_in[3];
  const float* emb_tim = (const float*)d_in[4];
  const float* Wih_e   = (const float*)d_in[5];
  const float* Whh_e   = (const float*)d_in[6];
  const float* bih_e   = (const float*)d_in[7];
  const float* bhh_e   = (const float*)d_in[8];
  const float* Wih_d   = (const float*)d_in[9];
  const float* Whh_d   = (const float*)d_in[10];
  const float* bih_d   = (const float*)d_in[11];
  const float* bhh_d   = (const float*)d_in[12];
  const float* W_fc    = (const float*)d_in[13];
  const float* b_fc    = (const float*)d_in[14];
  float* out = (float*)d_out;

  float* ws = (float*)d_ws;
  unsigned int* hbuf_e = (unsigned int*)ws;        // 2*1024 uint = 8 KB
  unsigned int* hbuf_d = (unsigned int*)(ws + 2048); // 2*1024 uint = 8 KB
  float* lse    = ws + 4096;                      // 1024
  float* x      = ws + 5120;                      // 4096*544
  float* gi_e   = x + (size_t)SEQ * IN_DIM;       // 3072*3072
  float* gi_d   = gi_e + (size_t)ENC_T * 3072;    // 1024*3072
  float* Hh     = gi_d + (size_t)TGT * 3072;      // 3072*1024
  float* HhT    = Hh + (size_t)ENC_T * HID;       // 1024*3072
  float* outcat = HhT + (size_t)HID * ENC_T;      // 1024*2048
  float* energ  = outcat + (size_t)TGT * 2048;    // 1024*3072 (attn in-place)

  // zero stamped h double-buffers (stamp 0 == "valid for t=0 read", h == 0)
  hipMemsetAsync(d_ws, 0, 4096 * sizeof(float), stream);

  embed_kernel<<<SEQ, 128, 0, stream>>>(loc, tim, emb_loc, emb_tim, x);

  // input-gate precompute: gi = x @ Wih^T + bih
  gemm_nt<<<dim3(ENC_T / 128, 3072 / 128), 256, 0, stream>>>(
      x, IN_DIM, Wih_e, IN_DIM, gi_e, 3072, bih_e, ENC_T, 3072, IN_DIM);
  gemm_nt<<<dim3(TGT / 128, 3072 / 128), 256, 0, stream>>>(
      x + (size_t)ENC_T * IN_DIM, IN_DIM, Wih_d, IN_DIM, gi_d, 3072, bih_d, TGT, 3072, IN_DIM);

  // sequential GRU scans (encoder + decoder concurrently)
  scan_kernel<<<2 * SC_WGS, 256, 0, stream>>>(Whh_e, bhh_e, gi_e, Whh_d, bhh_d, gi_d,
                                              Hh, HhT, outcat, hbuf_e, hbuf_d);

  // energies = Hs @ Hh^T
  gemm_nt<<<dim3(TGT / 128, ENC_T / 128), 256, 0, stream>>>(
      outcat, 2048, Hh, HID, energ, ENC_T, nullptr, TGT, ENC_T, HID);
  softmax_kernel<<<TGT, 256, 0, stream>>>(energ);
  // context = attn @ Hh  (= attn @ (Hh^T)^T), written into outcat cols 1024..2047
  gemm_nt<<<dim3(TGT / 128, HID / 128), 256, 0, stream>>>(
      energ, ENC_T, HhT, ENC_T, outcat + HID, 2048, nullptr, TGT, HID, ENC_T);

  // y = outcat @ W_fc^T + b_fc
  gemm_nt<<<dim3(TGT / 128, (NCLS + 127) / 128), 256, 0, stream>>>(
      outcat, 2048, W_fc, 2048, out, NCLS, b_fc, TGT, NCLS, 2048);

  // log_softmax
  lse_kernel<<<TGT, 256, 0, stream>>>(out, lse);
  sub_kernel<<<4096, 256, 0, stream>>>(out, lse);
}

// Round 5
// 14199.078 us; speedup vs baseline: 1.1963x; 1.1963x over previous
//
#include <hip/hip_runtime.h>
#include <hip/hip_bf16.h>
#include <cstdint>

typedef __attribute__((ext_vector_type(4))) float floatx4;
typedef __attribute__((ext_vector_type(8))) __bf16 bf16x8;
typedef __attribute__((ext_vector_type(4))) __bf16 bf16x4;
typedef unsigned long long u64t;

#define HID    1024
#define SEQ    4096
#define TGT    1024
#define ENC_T  3072
#define IN_DIM 544
#define NCLS   50000

// ---------------- embed: x = [emb_loc[loc] | emb_tim[tim]] ----------------
__global__ __launch_bounds__(128) void embed_kernel(
    const int* __restrict__ loc, const int* __restrict__ tim,
    const float* __restrict__ el, const float* __restrict__ et,
    float* __restrict__ x) {
  int row = blockIdx.x, t = threadIdx.x;
  int li = loc[row], ti = tim[row];
  float4 v = *(const float4*)(el + (size_t)li * 512 + t * 4);
  *(float4*)(x + (size_t)row * IN_DIM + t * 4) = v;
  if (t < 8) {
    float4 w = *(const float4*)(et + (size_t)ti * 32 + t * 4);
    *(float4*)(x + (size_t)row * IN_DIM + 512 + t * 4) = w;
  }
}

// ---------------- generic NT GEMM: C[M,N] = A[M,K] @ B[N,K]^T (+bias[n]) --
#define BK  64
#define LDT 72   // 64 + 8 bf16 pad; row stride 144 B (16-aligned)

__global__ __launch_bounds__(256) void gemm_nt(
    const float* __restrict__ A, int lda,
    const float* __restrict__ B, int ldb,
    float* __restrict__ C, int ldc,
    const float* __restrict__ bias,
    int M, int N, int K) {
  __shared__ __bf16 As[128 * LDT];
  __shared__ __bf16 Bs[128 * LDT];
  const int tid = threadIdx.x;
  const int bm = blockIdx.x * 128, bn = blockIdx.y * 128;
  const int wave = tid >> 6, lane = tid & 63;
  const int wm = (wave & 1) * 64, wn = (wave >> 1) * 64;
  const int fr = lane & 15;
  const int kq = (lane >> 4) * 8;

  floatx4 acc[4][4];
#pragma unroll
  for (int i = 0; i < 4; i++)
#pragma unroll
    for (int j = 0; j < 4; j++) acc[i][j] = (floatx4){0.f, 0.f, 0.f, 0.f};

  const int nkt = (K + BK - 1) / BK;
  for (int kt = 0; kt < nkt; ++kt) {
    const int k0 = kt * BK;
#pragma unroll
    for (int i = 0; i < 8; i++) {
      int flat = tid + i * 256;       // 2048 float4 slots: 128 rows x 16
      int r = flat >> 4;
      int c4 = (flat & 15) * 4;
      float4 va = {0, 0, 0, 0}, vb = {0, 0, 0, 0};
      if (k0 + c4 < K) {
        va = *(const float4*)(A + (size_t)(bm + r) * lda + k0 + c4);
        if (bn + r < N) vb = *(const float4*)(B + (size_t)(bn + r) * ldb + k0 + c4);
      }
      *(bf16x4*)(As + r * LDT + c4) =
          (bf16x4){(__bf16)va.x, (__bf16)va.y, (__bf16)va.z, (__bf16)va.w};
      *(bf16x4*)(Bs + r * LDT + c4) =
          (bf16x4){(__bf16)vb.x, (__bf16)vb.y, (__bf16)vb.z, (__bf16)vb.w};
    }
    __syncthreads();
#pragma unroll
    for (int kh = 0; kh < 2; ++kh) {
      const int kf = kh * 32 + kq;
      bf16x8 af[4], bfr[4];
#pragma unroll
      for (int i = 0; i < 4; i++) {
        af[i]  = *(const bf16x8*)(As + (wm + i * 16 + fr) * LDT + kf);
        bfr[i] = *(const bf16x8*)(Bs + (wn + i * 16 + fr) * LDT + kf);
      }
#pragma unroll
      for (int mi = 0; mi < 4; mi++)
#pragma unroll
        for (int ni = 0; ni < 4; ni++)
          acc[mi][ni] = __builtin_amdgcn_mfma_f32_16x16x32_bf16(
              af[mi], bfr[ni], acc[mi][ni], 0, 0, 0);
    }
    __syncthreads();
  }

  const int em = (lane >> 4) * 4;
#pragma unroll
  for (int mi = 0; mi < 4; mi++) {
#pragma unroll
    for (int ni = 0; ni < 4; ni++) {
      int gn = bn + wn + ni * 16 + fr;
      if (gn < N) {
        float bv = bias ? bias[gn] : 0.f;
        int gm = bm + wm + mi * 16 + em;
#pragma unroll
        for (int r2 = 0; r2 < 4; r2++)
          C[(size_t)(gm + r2) * ldc + gn] = acc[mi][ni][r2] + bv;
      }
    }
  }
}

// ---------------- persistent GRU scan (enc: WG 0..127, dec: WG 128..255) --
// Compact stamped-h protocol (round-4) + TWO-LEVEL EPOCH decongestion:
// a dedicated aggregator WG (block 256) min-reduces all stamps and publishes
// the global min to 16 replicated cache lines per scan. Readers poll ONE
// wave-uniform epoch word (1 coalesced line-request/wave/round, 16-way
// spread) instead of hammering the 64 data lines; the stamped-data load then
// happens ONCE per step. Stamps remain the correctness backstop (epoch is a
// throttle only). WAR safety: stamp t+1 from a wave is dependency-ordered
// after that wave's step-t data loads, so min-stamp >= t+1 implies every
// reader consumed the parity being overwritten at t+1.
#define SC_WGS 128

__device__ __forceinline__ float flo(unsigned int u) {
  return __builtin_bit_cast(float, u << 16);
}
__device__ __forceinline__ float fhi(unsigned int u) {
  return __builtin_bit_cast(float, u & 0xffff0000u);
}

__global__ __launch_bounds__(256) void scan_kernel(
    const float* __restrict__ Whh_e, const float* __restrict__ bhh_e, const float* __restrict__ gi_e,
    const float* __restrict__ Whh_d, const float* __restrict__ bhh_d, const float* __restrict__ gi_d,
    float* __restrict__ Hh, float* __restrict__ HhT, float* __restrict__ outcat,
    unsigned int* __restrict__ hbuf_e, unsigned int* __restrict__ hbuf_d,
    unsigned int* __restrict__ epoch) {
  const int tid = threadIdx.x;

  // ---------------- aggregator WG ----------------
  if (blockIdx.x == 2 * SC_WGS) {
    const int w = tid >> 6, l = tid & 63;
    if (w < 2) {
      const u64t* sp = (const u64t*)(w == 0 ? hbuf_e : hbuf_d);
      unsigned int* ep = epoch + (w == 0 ? 0 : 256);
      const unsigned int Ta = (w == 0) ? ENC_T : TGT;
      unsigned int last = 0;
      long arounds = 1L << 22;   // bounded: never hang
      while (last < Ta && --arounds > 0) {
        unsigned int mn = 0xffffffffu;
#pragma unroll
        for (int j = 0; j < 8; ++j) {
          u64t a = __hip_atomic_load(sp + l + 64 * j, __ATOMIC_RELAXED, __HIP_MEMORY_SCOPE_AGENT);
          u64t b = __hip_atomic_load(sp + 512 + l + 64 * j, __ATOMIC_RELAXED, __HIP_MEMORY_SCOPE_AGENT);
          unsigned int s0 = max((unsigned int)a >> 16, (unsigned int)b >> 16);
          unsigned int s1 = max((unsigned int)(a >> 32) >> 16, (unsigned int)(b >> 32) >> 16);
          mn = min(mn, min(s0, s1));
        }
#pragma unroll
        for (int o = 32; o; o >>= 1) {
          unsigned int m2 = (unsigned int)__shfl_xor((int)mn, o);
          mn = min(mn, m2);
        }
        if (mn > last) {
          last = mn;
          if (l < 16)
            __hip_atomic_store(ep + l * 16, mn, __ATOMIC_RELAXED, __HIP_MEMORY_SCOPE_AGENT);
        }
      }
    }
    return;
  }

  const bool enc = blockIdx.x < SC_WGS;
  const int wid = enc ? blockIdx.x : (blockIdx.x - SC_WGS);
  const int T = enc ? ENC_T : TGT;
  const float* Whh = enc ? Whh_e : Whh_d;
  const float* bhh = enc ? bhh_e : bhh_d;
  const float* gi  = enc ? gi_e : gi_d;
  unsigned int* hbuf = enc ? hbuf_e : hbuf_d;
  const unsigned int* myep = epoch + (enc ? 0 : 256) + (blockIdx.x & 15) * 16;

  // weights: per local elem (8): r,z packed bf16x2 (uint2) + n packed (uint)
  __shared__ uint2 wrz[8 * 512];          // 32 KB
  __shared__ unsigned int wnn[8 * 512];   // 16 KB

  for (int i = tid; i < 8 * 512; i += 256) {
    int el = i >> 9, k2 = i & 511;
    int rb = wid * 8 + el;
    float2 w0 = *(const float2*)(Whh + (size_t)(0 * HID + rb) * HID + 2 * k2);
    float2 w1 = *(const float2*)(Whh + (size_t)(1 * HID + rb) * HID + 2 * k2);
    float2 w2 = *(const float2*)(Whh + (size_t)(2 * HID + rb) * HID + 2 * k2);
    unsigned int p0 = (unsigned int)__builtin_bit_cast(unsigned short, (__bf16)w0.x) |
                      ((unsigned int)__builtin_bit_cast(unsigned short, (__bf16)w0.y) << 16);
    unsigned int p1 = (unsigned int)__builtin_bit_cast(unsigned short, (__bf16)w1.x) |
                      ((unsigned int)__builtin_bit_cast(unsigned short, (__bf16)w1.y) << 16);
    unsigned int p2 = (unsigned int)__builtin_bit_cast(unsigned short, (__bf16)w2.x) |
                      ((unsigned int)__builtin_bit_cast(unsigned short, (__bf16)w2.y) << 16);
    wrz[i] = make_uint2(p0, p1);
    wnn[i] = p2;
  }
  __syncthreads();

  const int l = tid & 63;          // lane in wave
  const int w = tid >> 6;          // wave 0..3
  const int le0 = w * 2, le1 = le0 + 1;   // local elems this wave owns
  const int e0 = wid * 8 + le0;

  float bq = 0.f;
  if (l < 3) bq = bhh[l * HID + e0];
  else if (l >= 4 && l < 7) bq = bhh[(l - 4) * HID + (e0 + 1)];

  const uint2* wrz0 = wrz + le0 * 512;
  const uint2* wrz1 = wrz + le1 * 512;
  const unsigned int* wnn0 = wnn + le0 * 512;
  const unsigned int* wnn1 = wnn + le1 * 512;

  float h_own = 0.f;        // fp32 recurrent state for element e0+l (l<2)
  long budget = 1L << 21;   // global failed-round budget: fast-fail, no hang

  for (int t = 0; t < T; ++t) {
    float gval = 0.f;  // input-gate prefetch (epoch-independent, overlaps poll)
    if (l < 3) gval = gi[(size_t)t * 3072 + l * HID + e0];
    else if (l >= 4 && l < 7) gval = gi[(size_t)t * 3072 + (l - 4) * HID + (e0 + 1)];

    // ---- level-1 wait: replicated epoch (1 coalesced line-request/round) --
    if (t > 0) {
      while (__hip_atomic_load(myep, __ATOMIC_RELAXED, __HIP_MEMORY_SCOPE_AGENT)
             < (unsigned int)t) {
        if (--budget < 0) break;
      }
      asm volatile("" ::: "memory");
    }

    // ---- level-2: one-shot stamped-data load (stamps = correctness) ------
    const u64t* hp = (const u64t*)(hbuf + ((t + 1) & 1) * HID);
    const unsigned int tlo = (unsigned int)t;
    float ar0, az0, an0, ar1, az1, an1;
    for (;;) {
      u64t hv[8];
#pragma unroll
      for (int j = 0; j < 8; ++j)
        hv[j] = __hip_atomic_load(hp + l + 64 * j, __ATOMIC_RELAXED, __HIP_MEMORY_SCOPE_AGENT);
      bool ok = true;
      ar0 = az0 = an0 = ar1 = az1 = an1 = 0.f;
#pragma unroll
      for (int j = 0; j < 8; ++j) {
        unsigned int w0 = (unsigned int)hv[j];
        unsigned int w1 = (unsigned int)(hv[j] >> 32);
        ok &= ((w0 >> 16) >= tlo) & ((w1 >> 16) >= tlo);
        float h0 = flo(w0);   // bf16 payload -> f32
        float h1 = flo(w1);
        int i = l + 64 * j;
        uint2 u0 = wrz0[i];
        unsigned int n0 = wnn0[i];
        uint2 u1 = wrz1[i];
        unsigned int n1 = wnn1[i];
        ar0 += flo(u0.x) * h0 + fhi(u0.x) * h1;
        az0 += flo(u0.y) * h0 + fhi(u0.y) * h1;
        an0 += flo(n0) * h0 + fhi(n0) * h1;
        ar1 += flo(u1.x) * h0 + fhi(u1.x) * h1;
        az1 += flo(u1.y) * h0 + fhi(u1.y) * h1;
        an1 += flo(n1) * h0 + fhi(n1) * h1;
      }
      if (__all(ok)) break;
      if (--budget < 0) break;   // bounded: fast wrong-result beats a hang
    }
    // full-wave butterfly reduce (each lane ends with the 6 sums)
#pragma unroll
    for (int o = 32; o; o >>= 1) {
      ar0 += __shfl_xor(ar0, o); az0 += __shfl_xor(az0, o); an0 += __shfl_xor(an0, o);
      ar1 += __shfl_xor(ar1, o); az1 += __shfl_xor(az1, o); an1 += __shfl_xor(an1, o);
    }
    int base = (l & 1) * 4;  // writer lane 0 -> gval lanes 0-2 (e0), lane 1 -> 4-6 (e0+1)
    float i_r = __shfl(gval, base + 0);
    float i_z = __shfl(gval, base + 1);
    float i_n = __shfl(gval, base + 2);
    float b_r = __shfl(bq, base + 0);
    float b_z = __shfl(bq, base + 1);
    float b_n = __shfl(bq, base + 2);
    if (l < 2) {
      float sr = l ? ar1 : ar0;
      float sz = l ? az1 : az0;
      float sn = l ? an1 : an0;
      int e = e0 + l;
      float r = 1.f / (1.f + expf(-(i_r + sr + b_r)));
      float z = 1.f / (1.f + expf(-(i_z + sz + b_z)));
      float nn2 = tanhf(i_n + r * (sn + b_n));
      float hnew = (1.f - z) * nn2 + z * h_own;
      h_own = hnew;
      unsigned int pk = ((unsigned int)(t + 1) << 16) |
                        (unsigned int)__builtin_bit_cast(unsigned short, (__bf16)hnew);
      __hip_atomic_store(&hbuf[(t & 1) * HID + e], pk,
                         __ATOMIC_RELAXED, __HIP_MEMORY_SCOPE_AGENT);
      if (enc) {
        Hh[(size_t)t * HID + e] = hnew;
        HhT[(size_t)e * ENC_T + t] = hnew;
      } else {
        outcat[(size_t)t * 2048 + e] = hnew;  // hidden_state -> out-concat cols 0..1023
      }
    }
  }
}

// ---------------- reductions ----------------
__device__ __forceinline__ float wave_max(float v) {
#pragma unroll
  for (int o = 32; o; o >>= 1) v = fmaxf(v, __shfl_xor(v, o));
  return v;
}
__device__ __forceinline__ float wave_sum(float v) {
#pragma unroll
  for (int o = 32; o; o >>= 1) v += __shfl_xor(v, o);
  return v;
}

// in-place row softmax over [TGT, ENC_T]
__global__ __launch_bounds__(256) void softmax_kernel(float* __restrict__ E) {
  __shared__ float red[4];
  int row = blockIdx.x;
  float* p = E + (size_t)row * ENC_T;
  int tid = threadIdx.x, wave = tid >> 6;
  float v[12];
  float m = -3.4e38f;
#pragma unroll
  for (int j = 0; j < 12; j++) { v[j] = p[tid + j * 256]; m = fmaxf(m, v[j]); }
  m = wave_max(m);
  if ((tid & 63) == 0) red[wave] = m;
  __syncthreads();
  m = fmaxf(fmaxf(red[0], red[1]), fmaxf(red[2], red[3]));
  __syncthreads();
  float s = 0.f;
#pragma unroll
  for (int j = 0; j < 12; j++) { v[j] = expf(v[j] - m); s += v[j]; }
  s = wave_sum(s);
  if ((tid & 63) == 0) red[wave] = s;
  __syncthreads();
  s = red[0] + red[1] + red[2] + red[3];
  float inv = 1.f / s;
#pragma unroll
  for (int j = 0; j < 12; j++) p[tid + j * 256] = v[j] * inv;
}

__global__ __launch_bounds__(256) void lse_kernel(const float* __restrict__ Y,
                                                  float* __restrict__ lse) {
  __shared__ float red[4];
  int row = blockIdx.x;
  const float* p = Y + (size_t)row * NCLS;
  int tid = threadIdx.x, wave = tid >> 6;
  float m = -3.4e38f;
  for (int c = tid; c < NCLS; c += 256) m = fmaxf(m, p[c]);
  m = wave_max(m);
  if ((tid & 63) == 0) red[wave] = m;
  __syncthreads();
  m = fmaxf(fmaxf(red[0], red[1]), fmaxf(red[2], red[3]));
  __syncthreads();
  float s = 0.f;
  for (int c = tid; c < NCLS; c += 256) s += expf(p[c] - m);
  s = wave_sum(s);
  if ((tid & 63) == 0) red[wave] = s;
  __syncthreads();
  if (tid == 0) lse[row] = m + logf(red[0] + red[1] + red[2] + red[3]);
}

__global__ __launch_bounds__(256) void sub_kernel(float* __restrict__ Y,
                                                  const float* __restrict__ lse) {
  const unsigned total = (unsigned)TGT * (NCLS / 4);
  unsigned stride = gridDim.x * 256;
  for (unsigned i = blockIdx.x * 256 + threadIdx.x; i < total; i += stride) {
    unsigned row = i / (NCLS / 4);
    float l = lse[row];
    float4 v = ((float4*)Y)[i];
    v.x -= l; v.y -= l; v.z -= l; v.w -= l;
    ((float4*)Y)[i] = v;
  }
}

// ---------------- launch ----------------
extern "C" void kernel_launch(void* const* d_in, const int* in_sizes, int n_in,
                              void* d_out, int out_size, void* d_ws, size_t ws_size,
                              hipStream_t stream) {
  const int*   loc     = (const int*)d_in[0];
  const int*   tim     = (const int*)d_in[1];
  // d_in[2] = target_len (fixed 1024, ignored)
  const float* emb_loc = (const float*)d_in[3];
  const float* emb_tim = (const float*)d_in[4];
  const float* Wih_e   = (const float*)d_in[5];
  const float* Whh_e   = (const float*)d_in[6];
  const float* bih_e   = (const float*)d_in[7];
  const float* bhh_e   = (const float*)d_in[8];
  const float* Wih_d   = (const float*)d_in[9];
  const float* Whh_d   = (const float*)d_in[10];
  const float* bih_d   = (const float*)d_in[11];
  const float* bhh_d   = (const float*)d_in[12];
  const float* W_fc    = (const float*)d_in[13];
  const float* b_fc    = (const float*)d_in[14];
  float* out = (float*)d_out;

  float* ws = (float*)d_ws;
  unsigned int* hbuf_e = (unsigned int*)ws;          // 2*1024 uint = 8 KB
  unsigned int* hbuf_d = (unsigned int*)(ws + 2048); // 2*1024 uint = 8 KB
  unsigned int* epoch  = (unsigned int*)(ws + 4096); // 512 uint: enc 16 lines, dec 16 lines
  float* lse    = ws + 4608;                      // 1024
  float* x      = ws + 5632;                      // 4096*544
  float* gi_e   = x + (size_t)SEQ * IN_DIM;       // 3072*3072
  float* gi_d   = gi_e + (size_t)ENC_T * 3072;    // 1024*3072
  float* Hh     = gi_d + (size_t)TGT * 3072;      // 3072*1024
  float* HhT    = Hh + (size_t)ENC_T * HID;       // 1024*3072
  float* outcat = HhT + (size_t)HID * ENC_T;      // 1024*2048
  float* energ  = outcat + (size_t)TGT * 2048;    // 1024*3072 (attn in-place)

  // zero stamped h double-buffers + epochs (stamp/epoch 0 == valid for t=0)
  hipMemsetAsync(d_ws, 0, 4608 * sizeof(float), stream);

  embed_kernel<<<SEQ, 128, 0, stream>>>(loc, tim, emb_loc, emb_tim, x);

  // input-gate precompute: gi = x @ Wih^T + bih
  gemm_nt<<<dim3(ENC_T / 128, 3072 / 128), 256, 0, stream>>>(
      x, IN_DIM, Wih_e, IN_DIM, gi_e, 3072, bih_e, ENC_T, 3072, IN_DIM);
  gemm_nt<<<dim3(TGT / 128, 3072 / 128), 256, 0, stream>>>(
      x + (size_t)ENC_T * IN_DIM, IN_DIM, Wih_d, IN_DIM, gi_d, 3072, bih_d, TGT, 3072, IN_DIM);

  // sequential GRU scans (encoder + decoder concurrently) + aggregator WG
  scan_kernel<<<2 * SC_WGS + 1, 256, 0, stream>>>(Whh_e, bhh_e, gi_e, Whh_d, bhh_d, gi_d,
                                                  Hh, HhT, outcat, hbuf_e, hbuf_d, epoch);

  // energies = Hs @ Hh^T
  gemm_nt<<<dim3(TGT / 128, ENC_T / 128), 256, 0, stream>>>(
      outcat, 2048, Hh, HID, energ, ENC_T, nullptr, TGT, ENC_T, HID);
  softmax_kernel<<<TGT, 256, 0, stream>>>(energ);
  // context = attn @ Hh  (= attn @ (Hh^T)^T), written into outcat cols 1024..2047
  gemm_nt<<<dim3(TGT / 128, HID / 128), 256, 0, stream>>>(
      energ, ENC_T, HhT, ENC_T, outcat + HID, 2048, nullptr, TGT, HID, ENC_T);

  // y = outcat @ W_fc^T + b_fc
  gemm_nt<<<dim3(TGT / 128, (NCLS + 127) / 128), 256, 0, stream>>>(
      outcat, 2048, W_fc, 2048, out, NCLS, b_fc, TGT, NCLS, 2048);

  // log_softmax
  lse_kernel<<<TGT, 256, 0, stream>>>(out, lse);
  sub_kernel<<<4096, 256, 0, stream>>>(out, lse);
}